// Round 1
// 501.785 us; speedup vs baseline: 1.1724x; 1.1724x over previous
//
#include <hip/hip_runtime.h>
#include <hip/hip_bf16.h>

typedef __bf16 bf16x8 __attribute__((ext_vector_type(8)));
typedef float f32x4 __attribute__((ext_vector_type(4)));
typedef _Float16 h8 __attribute__((ext_vector_type(8)));
typedef unsigned short u16x8 __attribute__((ext_vector_type(8)));

__device__ inline unsigned short f2b(float x) {
    __hip_bfloat16 h = __float2bfloat16(x);
    return __builtin_bit_cast(unsigned short, h);
}

__device__ inline void gload16(const void* g, void* l) {
    __builtin_amdgcn_global_load_lds(
        (const __attribute__((address_space(1))) unsigned int*)g,
        (__attribute__((address_space(3))) unsigned int*)l, 16, 0, 0);
}

// ---------------------------------------------------------------------------
// NT GEMM: C[M,N] = A[M,K] * B[N,K]^T (+bias), A/B bf16 K-contiguous.
// 256x256 tile, BK=32, 512 threads = 8 waves (2M x 4N), wave tile 128x64,
// mfma 16x16x32. Ring-4 LDS double... quad-buffer, prefetch distance 3,
// counted s_waitcnt vmcnt(12) (T3+T4) — never drains to 0 in the hot loop.
// LDS chunk swizzle: physical 16B slot = kslot ^ (row&3) ^ ((row>>2)&3);
// applied on the GLOBAL SOURCE (write side, stays within the row's 64B line)
// and on the ds_read address (read side) — linear global_load_lds dest (m104).
// Read conflict: 2-way per bank quad = free (m136). setprio around MFMA (T5).
// EPI: 0 = QKV router (bias, q/k normal, v transposed), 1 = f16*scale (scores),
//      2 = bf16 (PV->ao), 3 = f32+bias (final out)
// ---------------------------------------------------------------------------
template<int EPI, int SWZ>
__global__ __launch_bounds__(512, 2) void gemm_nt(
    const unsigned short* __restrict__ A, const unsigned short* __restrict__ B,
    long aZ, long bZ, int lda, int ldb, int K,
    const float* __restrict__ bias,
    void* __restrict__ C0, void* __restrict__ C1, void* __restrict__ C2,
    long cZ, int ldc, float scale, int gx, int gy)
{
    // 4 buffers x (A: 256x32 bf16 = 16KiB, B: 16KiB) = 128 KiB
    __shared__ __attribute__((aligned(16))) unsigned short lds[4][2][8192];

    int wgid;
    if (SWZ) {
        const int nwg = (int)gridDim.x;
        const int bid = (int)blockIdx.x;
        const int qch = nwg >> 3, rch = nwg & 7;
        const int xcd = bid & 7, idx = bid >> 3;
        wgid = (xcd < rch ? xcd * (qch + 1)
                          : rch * (qch + 1) + (xcd - rch) * qch) + idx;
    } else {
        wgid = (int)blockIdx.x;
    }
    const int bx = wgid % gx;
    const int rem = wgid / gx;
    const int by = rem % gy;
    const int z = rem / gy;

    const int t = threadIdx.x;
    const int lane = t & 63, wid = t >> 6;
    const int wr = wid >> 2, wc = wid & 3;           // 2 x 4 wave grid
    const int tileM = by * 256, tileN = bx * 256;
    A += (size_t)z * aZ;
    B += (size_t)z * bZ;

    f32x4 acc[8][4] = {};

    // ---- staging geometry: per matrix, 1024 chunks of 16B per K-tile.
    // physical chunk pc = li*512 + t  (li=0,1); row = pc>>2, pslot = pc&3.
    // source slot = pslot ^ S(row), S(row) = (row ^ (row>>2)) & 3.
    // (row+128 has same S, so one source-slot works for both li.)
    const int r0 = t >> 2;
    const int ps = t & 3;
    const int s0 = ps ^ ((r0 ^ (r0 >> 2)) & 3);
    const unsigned short* A0 = A + (size_t)(tileM + r0) * lda + s0 * 8;
    const unsigned short* A1 = A + (size_t)(tileM + 128 + r0) * lda + s0 * 8;
    const unsigned short* B0 = B + (size_t)(tileN + r0) * ldb + s0 * 8;
    const unsigned short* B1 = B + (size_t)(tileN + 128 + r0) * ldb + s0 * 8;

    // ---- read geometry: frag (row, kslot=lane>>4) lives at physical slot
    // kslot ^ S(row); S(row) folds to (lane&3)^((lane>>2)&3) for all frags.
    const int l4 = lane & 15;
    const int ks8 = (((lane >> 4) ^ (lane & 3) ^ ((lane >> 2) & 3)) & 3) * 8;
    const int arow = wr * 128 + l4;
    const int brow = wc * 64 + l4;

    auto stage = [&](int kt) {
        const int b = kt & 3;
        const int ko = kt * 32;                       // ushort offset along K
        char* baseA = (char*)&lds[b][0][0];
        char* baseB = (char*)&lds[b][1][0];
        gload16(A0 + ko, baseA + wid * 1024);
        gload16(A1 + ko, baseA + 8192 + wid * 1024);
        gload16(B0 + ko, baseB + wid * 1024);
        gload16(B1 + ko, baseB + 8192 + wid * 1024);
    };

    auto body = [&](int kt) {
        // barrier A: all waves' loads for tile kt have landed (each wave did
        // its own counted vmcnt before arriving). asm+memory clobber keeps
        // the ds_reads below from being hoisted above the rendezvous.
        asm volatile("s_barrier" ::: "memory");
        const unsigned short* As = &lds[kt & 3][0][0];
        const unsigned short* Bs = &lds[kt & 3][1][0];
        bf16x8 bfr[4], af[8];
#pragma unroll
        for (int n = 0; n < 4; ++n)
            bfr[n] = *(const bf16x8*)(Bs + (brow + n * 16) * 32 + ks8);
#pragma unroll
        for (int m = 0; m < 8; ++m)
            af[m] = *(const bf16x8*)(As + (arow + m * 16) * 32 + ks8);
        __builtin_amdgcn_s_setprio(1);
#pragma unroll
        for (int m = 0; m < 8; ++m)
#pragma unroll
            for (int n = 0; n < 4; ++n)
                acc[m][n] = __builtin_amdgcn_mfma_f32_16x16x32_bf16(
                    af[m], bfr[n], acc[m][n], 0, 0, 0);
        __builtin_amdgcn_s_setprio(0);
        // barrier B: all waves consumed tile kt from LDS (MFMA issue forces
        // lgkm drain) -> buffer (kt&3) may be overwritten by stage(kt+4).
        asm volatile("s_barrier" ::: "memory");
    };

    const int NT = K >> 5;                            // K multiple of 32, NT>=4
    stage(0); stage(1); stage(2);
    int kt = 0;
    for (; kt + 3 < NT; ++kt) {
        stage(kt + 3);                                // 16 outstanding now
        asm volatile("s_waitcnt vmcnt(12)" ::: "memory");  // tile kt landed
        body(kt);
    }
    for (; kt < NT; ++kt) {                           // 3-iter drain tail
        const int ahead = NT - 1 - kt;
        if (ahead == 2)      asm volatile("s_waitcnt vmcnt(8)" ::: "memory");
        else if (ahead == 1) asm volatile("s_waitcnt vmcnt(4)" ::: "memory");
        else                 asm volatile("s_waitcnt vmcnt(0)" ::: "memory");
        body(kt);
    }

    // epilogue: C/D layout col = lane&15, row = (lane>>4)*4 + j  [m89-verified]
    const int lr = lane >> 4, lc = lane & 15;
#pragma unroll
    for (int m = 0; m < 8; ++m) {
#pragma unroll
        for (int n = 0; n < 4; ++n) {
            f32x4 v = acc[m][n];
            const int col = tileN + wc * 64 + n * 16 + lc;
            const int row0 = tileM + wr * 128 + m * 16 + lr * 4;
            if (EPI == 0) {
                const float bv = bias[col];
                if (col < 2048) {
                    unsigned short* dst = (col < 1024) ? (unsigned short*)C0
                                                       : (unsigned short*)C1;
                    const int cc = col & 1023;
#pragma unroll
                    for (int j = 0; j < 4; ++j)
                        dst[(size_t)(row0 + j) * 1024 + cc] = f2b(v[j] + bv);
                } else {
                    // vT[b][col-2048][s], rows row0..row0+3 are consecutive s
                    const int b = row0 >> 12, s = row0 & 4095;
                    ushort4 h4;
                    h4.x = f2b(v[0] + bv); h4.y = f2b(v[1] + bv);
                    h4.z = f2b(v[2] + bv); h4.w = f2b(v[3] + bv);
                    *(ushort4*)((unsigned short*)C2 +
                                ((size_t)b * 1024 + (col - 2048)) * 4096 + s) = h4;
                }
            } else if (EPI == 1) {
#pragma unroll
                for (int j = 0; j < 4; ++j)
                    ((_Float16*)C0)[(size_t)z * cZ + (size_t)(row0 + j) * ldc + col] =
                        (_Float16)(v[j] * scale);
            } else if (EPI == 2) {
#pragma unroll
                for (int j = 0; j < 4; ++j)
                    ((unsigned short*)C0)[(size_t)z * cZ + (size_t)(row0 + j) * ldc + col] =
                        f2b(v[j]);
            } else {
#pragma unroll
                for (int j = 0; j < 4; ++j)
                    ((float*)C0)[(size_t)(row0 + j) * ldc + col] = v[j] + bias[col];
            }
        }
    }
}

// ---------------------------------------------------------------------------
// Row softmax in-place: reads 4096 f16, writes 4096 bf16 over the same bytes.
// ---------------------------------------------------------------------------
__global__ __launch_bounds__(256) void softmax_rows(unsigned short* __restrict__ sc)
{
    const size_t rowoff = (size_t)blockIdx.x * 4096;
    const int t = threadIdx.x;

    h8 a = *(const h8*)(sc + rowoff + t * 8);
    h8 b = *(const h8*)(sc + rowoff + 2048 + t * 8);
    float v[16];
#pragma unroll
    for (int i = 0; i < 8; ++i) { v[i] = (float)a[i]; v[8 + i] = (float)b[i]; }

    float mx = -1e30f;
#pragma unroll
    for (int i = 0; i < 16; ++i) mx = fmaxf(mx, v[i]);
#pragma unroll
    for (int o = 32; o > 0; o >>= 1) mx = fmaxf(mx, __shfl_xor(mx, o));
    __shared__ float redm[4];
    if ((t & 63) == 0) redm[t >> 6] = mx;
    __syncthreads();
    mx = fmaxf(fmaxf(redm[0], redm[1]), fmaxf(redm[2], redm[3]));

    float sum = 0.f;
#pragma unroll
    for (int i = 0; i < 16; ++i) { v[i] = expf(v[i] - mx); sum += v[i]; }
#pragma unroll
    for (int o = 32; o > 0; o >>= 1) sum += __shfl_xor(sum, o);
    __shared__ float reds[4];
    if ((t & 63) == 0) reds[t >> 6] = sum;
    __syncthreads();
    sum = reds[0] + reds[1] + reds[2] + reds[3];
    const float rs = 1.f / sum;

    u16x8 w0, w1;
#pragma unroll
    for (int i = 0; i < 8; ++i) {
        w0[i] = f2b(v[i] * rs);
        w1[i] = f2b(v[8 + i] * rs);
    }
    *(u16x8*)(sc + rowoff + t * 8) = w0;
    *(u16x8*)(sc + rowoff + 2048 + t * 8) = w1;
}

__global__ __launch_bounds__(256) void cast_bf16(
    const float* __restrict__ in, unsigned short* __restrict__ out, int n4)
{
    const int i = blockIdx.x * 256 + threadIdx.x;
    if (i < n4) {
        float4 f = ((const float4*)in)[i];
        ushort4 o;
        o.x = f2b(f.x); o.y = f2b(f.y); o.z = f2b(f.z); o.w = f2b(f.w);
        ((ushort4*)out)[i] = o;
    }
}

// ---------------------------------------------------------------------------
extern "C" void kernel_launch(void* const* d_in, const int* in_sizes, int n_in,
                              void* d_out, int out_size, void* d_ws, size_t ws_size,
                              hipStream_t stream)
{
    const float* x      = (const float*)d_in[0];   // [4,4096,1024]
    const float* qkv_w  = (const float*)d_in[1];   // [3072,1024]
    const float* qkv_b  = (const float*)d_in[2];   // [3072]
    const float* out_w  = (const float*)d_in[3];   // [1024,1024]
    const float* out_b  = (const float*)d_in[4];   // [1024]
    float* out = (float*)d_out;                    // [4,4096,1024] fp32

    unsigned short* W = (unsigned short*)d_ws;
    const size_t M16 = 16777216;   // one [4,4096,1024] bf16 tensor (ushorts)

    if (ws_size >= 236978176ull) {
        // ---- big mode: 226 MiB peak ----
        unsigned short* sc   = W;
        unsigned short* q    = sc + 67108864;
        unsigned short* kk   = q + M16;
        unsigned short* vT   = kk + M16;
        unsigned short* wo   = vT + M16;
        unsigned short* xb   = sc;            // transient, dead before sc write
        unsigned short* wqkv = sc + M16;      // transient
        unsigned short* ao   = q;             // q dead after scores GEMM

        cast_bf16<<<16384, 256, 0, stream>>>(x, xb, 4194304);
        cast_bf16<<<3072, 256, 0, stream>>>(qkv_w, wqkv, 786432);
        cast_bf16<<<1024, 256, 0, stream>>>(out_w, wo, 262144);

        gemm_nt<0, 0><<<12 * 64, 512, 0, stream>>>(
            xb, wqkv, 0, 0, 1024, 1024, 1024, qkv_b, q, kk, vT, 0, 0, 0.f, 12, 64);

        gemm_nt<1, 0><<<16 * 16 * 4, 512, 0, stream>>>(
            q, kk, 4194304, 4194304, 1024, 1024, 1024, nullptr,
            sc, nullptr, nullptr, 16777216, 4096, 0.03125f, 16, 16);

        softmax_rows<<<16384, 256, 0, stream>>>(sc);

        gemm_nt<2, 1><<<4 * 16 * 4, 512, 0, stream>>>(
            sc, vT, 16777216, 4194304, 4096, 4096, 4096, nullptr,
            ao, nullptr, nullptr, 4194304, 1024, 0.f, 4, 16);

        gemm_nt<3, 0><<<4 * 64, 512, 0, stream>>>(
            ao, wo, 0, 0, 1024, 1024, 1024, out_b,
            out, nullptr, nullptr, 0, 1024, 0.f, 4, 64);
    } else {
        // ---- small mode: 168 MiB peak, per-batch scores buffer ----
        unsigned short* sc   = W;
        unsigned short* q    = sc + M16;
        unsigned short* kk   = q + M16;
        unsigned short* vT   = kk + M16;
        unsigned short* ao   = vT + M16;
        unsigned short* wo   = ao + M16;
        unsigned short* wqkv = wo + 1048576;
        unsigned short* xb   = sc;

        cast_bf16<<<16384, 256, 0, stream>>>(x, xb, 4194304);
        cast_bf16<<<3072, 256, 0, stream>>>(qkv_w, wqkv, 786432);
        cast_bf16<<<1024, 256, 0, stream>>>(out_w, wo, 262144);

        gemm_nt<0, 0><<<12 * 64, 512, 0, stream>>>(
            xb, wqkv, 0, 0, 1024, 1024, 1024, qkv_b, q, kk, vT, 0, 0, 0.f, 12, 64);

        for (int z = 0; z < 4; ++z) {
            const size_t zo = (size_t)z * 4194304;
            gemm_nt<1, 0><<<16 * 16, 512, 0, stream>>>(
                q + zo, kk + zo, 0, 0, 1024, 1024, 1024, nullptr,
                sc, nullptr, nullptr, 0, 4096, 0.03125f, 16, 16);
            softmax_rows<<<4096, 256, 0, stream>>>(sc);
            gemm_nt<2, 1><<<4 * 16, 512, 0, stream>>>(
                sc, vT + zo, 0, 0, 4096, 4096, 4096, nullptr,
                ao + zo, nullptr, nullptr, 0, 1024, 0.f, 4, 16);
        }

        gemm_nt<3, 0><<<4 * 64, 512, 0, stream>>>(
            ao, wo, 0, 0, 1024, 1024, 1024, out_b,
            out, nullptr, nullptr, 0, 1024, 0.f, 4, 64);
    }
}

// Round 2
// 468.231 us; speedup vs baseline: 1.2564x; 1.0717x over previous
//
#include <hip/hip_runtime.h>
#include <hip/hip_bf16.h>

typedef __bf16 bf16x8 __attribute__((ext_vector_type(8)));
typedef float f32x4 __attribute__((ext_vector_type(4)));
typedef _Float16 h8 __attribute__((ext_vector_type(8)));
typedef unsigned short u16x8 __attribute__((ext_vector_type(8)));

__device__ inline unsigned short f2b(float x) {
    __hip_bfloat16 h = __float2bfloat16(x);
    return __builtin_bit_cast(unsigned short, h);
}

__device__ inline void gload16(const void* g, void* l) {
    __builtin_amdgcn_global_load_lds(
        (const __attribute__((address_space(1))) unsigned int*)g,
        (__attribute__((address_space(3))) unsigned int*)l, 16, 0, 0);
}

// ---------------------------------------------------------------------------
// NT GEMM: C[M,N] = A[M,K] * B[N,K]^T (+bias), A/B bf16 K-contiguous.
// m201-style 8-phase schedule: 256x256 tile, BK=64, 512 threads = 8 waves
// (2M x 4N), wave tile 128x64, mfma 16x16x32.
// LDS = 2 tile-buffers x 4 half-tiles [A0,A1,B0,B1] x 16KiB = 128 KiB.
// Per K-tile: 4 phases {ds_read m-quadrant frags; stage 1 half-tile; barrier;
// lgkmcnt(0); setprio(1); 16 MFMA; setprio(0); barrier}. B frags read once at
// P0 and held in regs. Staging leads: A(t+1) at P0/P1 (A slots busy all 4
// phases -> max lead 4), B(t+2) at P2/P3 (B slots free after P0 -> lead 6-7).
// One counted vmcnt(4) per K-tile at P3 (2 newest B half-tiles may stay in
// flight) -> confirms tile t+1 fully landed before any wave reads it (vmcnt
// precedes P3's barriers). Tail: vmcnt(0) when no B staged this iter.
// LDS swizzle (both-sides, rule 21): 16B granule g' = g ^ (row&7); row stride
// 128 B so bank depends only on g' -> wave read spreads evenly over 32 banks.
// Source pre-swizzled (stays inside the row's 128B line -> coalescing kept),
// global_load_lds dest linear, ds_read applies the same involution.
// EPI: 0 = QKV router (bias, q/k normal, v transposed), 1 = f16*scale (scores),
//      2 = bf16 (PV->ao), 3 = f32+bias (final out)
// ---------------------------------------------------------------------------
template<int EPI, int SWZ>
__global__ __launch_bounds__(512, 2) void gemm_nt(
    const unsigned short* __restrict__ A, const unsigned short* __restrict__ B,
    long aZ, long bZ, int lda, int ldb, int K,
    const float* __restrict__ bias,
    void* __restrict__ C0, void* __restrict__ C1, void* __restrict__ C2,
    long cZ, int ldc, float scale, int gx, int gy)
{
    __shared__ __attribute__((aligned(16))) unsigned short lds[2][4][8192];

    int wgid;
    if (SWZ) {
        const int nwg = (int)gridDim.x;
        const int bid = (int)blockIdx.x;
        const int qch = nwg >> 3, rch = nwg & 7;
        const int xcd = bid & 7, idx = bid >> 3;
        wgid = (xcd < rch ? xcd * (qch + 1)
                          : rch * (qch + 1) + (xcd - rch) * qch) + idx;
    } else {
        wgid = (int)blockIdx.x;
    }
    const int bx = wgid % gx;
    const int rem = wgid / gx;
    const int by = rem % gy;
    const int z = rem / gy;

    const int t = threadIdx.x;
    const int lane = t & 63, wid = t >> 6;
    const int wr = wid >> 2, wc = wid & 3;           // 2 x 4 wave grid
    const int wc1 = wc & 1, wch = wc >> 1;
    const int tileM = by * 256, tileN = bx * 256;
    A += (size_t)z * aZ;
    B += (size_t)z * bZ;

    f32x4 acc[8][4] = {};

    // ---- read geometry: frag element k = ks*32 + qw*8 (qw = lane>>4);
    // granule g = ks*4+qw; physical granule g^(row&7), row&7 == lane&7.
    const int l4 = lane & 15, qw = lane >> 4, sw = lane & 7;
    const int aoff0 = l4 * 64 + ((qw ^ sw) << 3);
    const int aoff1 = l4 * 64 + (((4 | qw) ^ sw) << 3);

    // ---- staging geometry: half-tile = 128 rows x 64 K = 16 KiB, 2 loads/thr.
    // chunk c = i*512 + t: LDS row = i*64 + (t>>3), phys granule = t&7,
    // source granule = (t&7) ^ (row&7) = (t ^ (t>>3)) & 7  (i*64 = 0 mod 8).
    const int srow = t >> 3;
    const int sg = ((t ^ (t >> 3)) & 7) << 3;
    const unsigned short* Asrc = A + (size_t)(tileM + srow) * lda + sg;
    const unsigned short* Bsrc = B + (size_t)(tileN + srow) * ldb + sg;

    auto stageA = [&](int kt, int h) {
        char* dst = (char*)&lds[kt & 1][h][0] + wid * 1024;
        const unsigned short* s = Asrc + (size_t)(h * 128) * lda + kt * 64;
        gload16(s, dst);
        gload16(s + (size_t)64 * lda, dst + 8192);
    };
    auto stageB = [&](int kt, int h) {
        char* dst = (char*)&lds[kt & 1][2 + h][0] + wid * 1024;
        const unsigned short* s = Bsrc + (size_t)(h * 128) * ldb + kt * 64;
        gload16(s, dst);
        gload16(s + (size_t)64 * ldb, dst + 8192);
    };

    const int NT = K >> 6;                            // BK = 64, K % 64 == 0
    // prologue: B(0), A(0), B(1)  (oldest-first order matters for vmcnt)
    stageB(0, 0); stageB(0, 1); stageA(0, 0); stageA(0, 1);
    if (NT > 1) {
        stageB(1, 0); stageB(1, 1);
        asm volatile("s_waitcnt vmcnt(4)" ::: "memory");  // tile 0 landed
    } else {
        asm volatile("s_waitcnt vmcnt(0)" ::: "memory");
    }
    asm volatile("s_barrier" ::: "memory");

    for (int kt = 0; kt < NT; ++kt) {
        const unsigned short* Ah = &lds[kt & 1][wr][0];
        const unsigned short* Bh = &lds[kt & 1][2 + wch][0] + wc1 * 4096;
        bf16x8 bfr[4][2], af[2][2];
#pragma unroll
        for (int p = 0; p < 4; ++p) {
            if (p == 0) {
#pragma unroll
                for (int n = 0; n < 4; ++n) {
                    bfr[n][0] = *(const bf16x8*)(Bh + n * 1024 + aoff0);
                    bfr[n][1] = *(const bf16x8*)(Bh + n * 1024 + aoff1);
                }
            }
#pragma unroll
            for (int i = 0; i < 2; ++i) {
                af[i][0] = *(const bf16x8*)(Ah + (p * 2 + i) * 1024 + aoff0);
                af[i][1] = *(const bf16x8*)(Ah + (p * 2 + i) * 1024 + aoff1);
            }
            if (p == 0 && kt + 1 < NT) stageA(kt + 1, 0);
            if (p == 1 && kt + 1 < NT) stageA(kt + 1, 1);
            if (p == 2 && kt + 2 < NT) stageB(kt + 2, 0);
            if (p == 3 && kt + 2 < NT) stageB(kt + 2, 1);
            if (p == 3 && kt + 1 < NT) {
                if (kt + 2 < NT) asm volatile("s_waitcnt vmcnt(4)" ::: "memory");
                else             asm volatile("s_waitcnt vmcnt(0)" ::: "memory");
            }
            asm volatile("s_barrier" ::: "memory");
            asm volatile("s_waitcnt lgkmcnt(0)" ::: "memory");
            __builtin_amdgcn_s_setprio(1);
#pragma unroll
            for (int i = 0; i < 2; ++i)
#pragma unroll
                for (int n = 0; n < 4; ++n) {
                    acc[p * 2 + i][n] = __builtin_amdgcn_mfma_f32_16x16x32_bf16(
                        af[i][0], bfr[n][0], acc[p * 2 + i][n], 0, 0, 0);
                    acc[p * 2 + i][n] = __builtin_amdgcn_mfma_f32_16x16x32_bf16(
                        af[i][1], bfr[n][1], acc[p * 2 + i][n], 0, 0, 0);
                }
            __builtin_amdgcn_s_setprio(0);
            asm volatile("s_barrier" ::: "memory");
        }
    }

    // epilogue: C/D layout col = lane&15, row = (lane>>4)*4 + j  [m89-verified]
    const int lr = lane >> 4, lc = lane & 15;
#pragma unroll
    for (int m = 0; m < 8; ++m) {
#pragma unroll
        for (int n = 0; n < 4; ++n) {
            f32x4 v = acc[m][n];
            const int col = tileN + wc * 64 + n * 16 + lc;
            const int row0 = tileM + wr * 128 + m * 16 + lr * 4;
            if (EPI == 0) {
                const float bv = bias[col];
                if (col < 2048) {
                    unsigned short* dst = (col < 1024) ? (unsigned short*)C0
                                                       : (unsigned short*)C1;
                    const int cc = col & 1023;
#pragma unroll
                    for (int j = 0; j < 4; ++j)
                        dst[(size_t)(row0 + j) * 1024 + cc] = f2b(v[j] + bv);
                } else {
                    // vT[b][col-2048][s], rows row0..row0+3 are consecutive s
                    const int b = row0 >> 12, s = row0 & 4095;
                    ushort4 h4;
                    h4.x = f2b(v[0] + bv); h4.y = f2b(v[1] + bv);
                    h4.z = f2b(v[2] + bv); h4.w = f2b(v[3] + bv);
                    *(ushort4*)((unsigned short*)C2 +
                                ((size_t)b * 1024 + (col - 2048)) * 4096 + s) = h4;
                }
            } else if (EPI == 1) {
#pragma unroll
                for (int j = 0; j < 4; ++j)
                    ((_Float16*)C0)[(size_t)z * cZ + (size_t)(row0 + j) * ldc + col] =
                        (_Float16)(v[j] * scale);
            } else if (EPI == 2) {
#pragma unroll
                for (int j = 0; j < 4; ++j)
                    ((unsigned short*)C0)[(size_t)z * cZ + (size_t)(row0 + j) * ldc + col] =
                        f2b(v[j]);
            } else {
#pragma unroll
                for (int j = 0; j < 4; ++j)
                    ((float*)C0)[(size_t)(row0 + j) * ldc + col] = v[j] + bias[col];
            }
        }
    }
}

// ---------------------------------------------------------------------------
// Row softmax in-place: reads 4096 f16, writes 4096 bf16 over the same bytes.
// ---------------------------------------------------------------------------
__global__ __launch_bounds__(256) void softmax_rows(unsigned short* __restrict__ sc)
{
    const size_t rowoff = (size_t)blockIdx.x * 4096;
    const int t = threadIdx.x;

    h8 a = *(const h8*)(sc + rowoff + t * 8);
    h8 b = *(const h8*)(sc + rowoff + 2048 + t * 8);
    float v[16];
#pragma unroll
    for (int i = 0; i < 8; ++i) { v[i] = (float)a[i]; v[8 + i] = (float)b[i]; }

    float mx = -1e30f;
#pragma unroll
    for (int i = 0; i < 16; ++i) mx = fmaxf(mx, v[i]);
#pragma unroll
    for (int o = 32; o > 0; o >>= 1) mx = fmaxf(mx, __shfl_xor(mx, o));
    __shared__ float redm[4];
    if ((t & 63) == 0) redm[t >> 6] = mx;
    __syncthreads();
    mx = fmaxf(fmaxf(redm[0], redm[1]), fmaxf(redm[2], redm[3]));

    float sum = 0.f;
#pragma unroll
    for (int i = 0; i < 16; ++i) { v[i] = expf(v[i] - mx); sum += v[i]; }
#pragma unroll
    for (int o = 32; o > 0; o >>= 1) sum += __shfl_xor(sum, o);
    __shared__ float reds[4];
    if ((t & 63) == 0) reds[t >> 6] = sum;
    __syncthreads();
    sum = reds[0] + reds[1] + reds[2] + reds[3];
    const float rs = 1.f / sum;

    u16x8 w0, w1;
#pragma unroll
    for (int i = 0; i < 8; ++i) {
        w0[i] = f2b(v[i] * rs);
        w1[i] = f2b(v[8 + i] * rs);
    }
    *(u16x8*)(sc + rowoff + t * 8) = w0;
    *(u16x8*)(sc + rowoff + 2048 + t * 8) = w1;
}

__global__ __launch_bounds__(256) void cast_bf16(
    const float* __restrict__ in, unsigned short* __restrict__ out, int n4)
{
    const int i = blockIdx.x * 256 + threadIdx.x;
    if (i < n4) {
        float4 f = ((const float4*)in)[i];
        ushort4 o;
        o.x = f2b(f.x); o.y = f2b(f.y); o.z = f2b(f.z); o.w = f2b(f.w);
        ((ushort4*)out)[i] = o;
    }
}

// ---------------------------------------------------------------------------
extern "C" void kernel_launch(void* const* d_in, const int* in_sizes, int n_in,
                              void* d_out, int out_size, void* d_ws, size_t ws_size,
                              hipStream_t stream)
{
    const float* x      = (const float*)d_in[0];   // [4,4096,1024]
    const float* qkv_w  = (const float*)d_in[1];   // [3072,1024]
    const float* qkv_b  = (const float*)d_in[2];   // [3072]
    const float* out_w  = (const float*)d_in[3];   // [1024,1024]
    const float* out_b  = (const float*)d_in[4];   // [1024]
    float* out = (float*)d_out;                    // [4,4096,1024] fp32

    unsigned short* W = (unsigned short*)d_ws;
    const size_t M16 = 16777216;   // one [4,4096,1024] bf16 tensor (ushorts)

    if (ws_size >= 236978176ull) {
        // ---- big mode: 226 MiB peak ----
        unsigned short* sc   = W;
        unsigned short* q    = sc + 67108864;
        unsigned short* kk   = q + M16;
        unsigned short* vT   = kk + M16;
        unsigned short* wo   = vT + M16;
        unsigned short* xb   = sc;            // transient, dead before sc write
        unsigned short* wqkv = sc + M16;      // transient
        unsigned short* ao   = q;             // q dead after scores GEMM

        cast_bf16<<<16384, 256, 0, stream>>>(x, xb, 4194304);
        cast_bf16<<<3072, 256, 0, stream>>>(qkv_w, wqkv, 786432);
        cast_bf16<<<1024, 256, 0, stream>>>(out_w, wo, 262144);

        gemm_nt<0, 0><<<12 * 64, 512, 0, stream>>>(
            xb, wqkv, 0, 0, 1024, 1024, 1024, qkv_b, q, kk, vT, 0, 0, 0.f, 12, 64);

        gemm_nt<1, 0><<<16 * 16 * 4, 512, 0, stream>>>(
            q, kk, 4194304, 4194304, 1024, 1024, 1024, nullptr,
            sc, nullptr, nullptr, 16777216, 4096, 0.03125f, 16, 16);

        softmax_rows<<<16384, 256, 0, stream>>>(sc);

        gemm_nt<2, 1><<<4 * 16 * 4, 512, 0, stream>>>(
            sc, vT, 16777216, 4194304, 4096, 4096, 4096, nullptr,
            ao, nullptr, nullptr, 4194304, 1024, 0.f, 4, 16);

        gemm_nt<3, 0><<<4 * 64, 512, 0, stream>>>(
            ao, wo, 0, 0, 1024, 1024, 1024, out_b,
            out, nullptr, nullptr, 0, 1024, 0.f, 4, 64);
    } else {
        // ---- small mode: 168 MiB peak, per-batch scores buffer ----
        unsigned short* sc   = W;
        unsigned short* q    = sc + M16;
        unsigned short* kk   = q + M16;
        unsigned short* vT   = kk + M16;
        unsigned short* ao   = vT + M16;
        unsigned short* wo   = ao + M16;
        unsigned short* wqkv = wo + 1048576;
        unsigned short* xb   = sc;

        cast_bf16<<<16384, 256, 0, stream>>>(x, xb, 4194304);
        cast_bf16<<<3072, 256, 0, stream>>>(qkv_w, wqkv, 786432);
        cast_bf16<<<1024, 256, 0, stream>>>(out_w, wo, 262144);

        gemm_nt<0, 0><<<12 * 64, 512, 0, stream>>>(
            xb, wqkv, 0, 0, 1024, 1024, 1024, qkv_b, q, kk, vT, 0, 0, 0.f, 12, 64);

        for (int z = 0; z < 4; ++z) {
            const size_t zo = (size_t)z * 4194304;
            gemm_nt<1, 0><<<16 * 16, 512, 0, stream>>>(
                q + zo, kk + zo, 0, 0, 1024, 1024, 1024, nullptr,
                sc, nullptr, nullptr, 0, 4096, 0.03125f, 16, 16);
            softmax_rows<<<4096, 256, 0, stream>>>(sc);
            gemm_nt<2, 1><<<4 * 16, 512, 0, stream>>>(
                sc, vT + zo, 0, 0, 4096, 4096, 4096, nullptr,
                ao + zo, nullptr, nullptr, 0, 1024, 0.f, 4, 16);
        }

        gemm_nt<3, 0><<<4 * 64, 512, 0, stream>>>(
            ao, wo, 0, 0, 1024, 1024, 1024, out_b,
            out, nullptr, nullptr, 0, 1024, 0.f, 4, 64);
    }
}